// Round 13
// baseline (157.975 us; speedup 1.0000x reference)
//
#include <hip/hip_runtime.h>

#define D 128

typedef short s16x8 __attribute__((ext_vector_type(8)));
typedef ushort u16x8 __attribute__((ext_vector_type(8)));
typedef float f32x4 __attribute__((ext_vector_type(4)));

static __device__ __forceinline__ float bf2f(ushort h) {
    return __uint_as_float(((uint)h) << 16);
}
static __device__ __forceinline__ ushort f2bf(float f) {
    uint u = __float_as_uint(f);
    u += 0x7fffu + ((u >> 16) & 1u);   // RNE
    return (ushort)(u >> 16);
}

// ---------------- prep: x->bf16  +  degree count  +  W pack ----------------
__global__ void prep_kernel(const float4* __restrict__ x4, ushort4* __restrict__ xh4, int n4,
                            const int* __restrict__ dst, int* __restrict__ cnt, int E,
                            const float* __restrict__ W1, const float* __restrict__ W2,
                            ushort* __restrict__ wp) {
    int tid = blockIdx.x * blockDim.x + threadIdx.x;
    int stride = gridDim.x * blockDim.x;
    for (int i = tid; i < n4; i += stride) {
        float4 v = x4[i];
        ushort4 h;
        h.x = f2bf(v.x); h.y = f2bf(v.y); h.z = f2bf(v.z); h.w = f2bf(v.w);
        xh4[i] = h;
    }
    for (int e = tid; e < E; e += stride) atomicAdd(&cnt[dst[e]], 1);
    if (tid < 4096) {
        int m = tid >> 11;
        int r = tid & 2047;
        int lane = r & 63;
        int nf = (r >> 6) & 7;
        int ks = r >> 9;
        const float* W = m ? W2 : W1;
        ushort* o = wp + m * 16384;
        int k0 = ks * 32 + ((lane >> 4) << 3);
        int c = nf * 16 + (lane & 15);
        #pragma unroll
        for (int i = 0; i < 8; ++i) o[r * 8 + i] = f2bf(W[(k0 + i) * D + c]);
    }
}

// ---------------- CSR alloc + fill ----------------
__global__ void alloc_kernel(const int* __restrict__ cnt, int* __restrict__ start,
                             int* __restrict__ cur, int* __restrict__ total, int n) {
    int i = blockIdx.x * blockDim.x + threadIdx.x;
    int lane = threadIdx.x & 63;
    int c = (i < n) ? cnt[i] : 0;
    int inc = c;
    #pragma unroll
    for (int s = 1; s < 64; s <<= 1) {
        int u = __shfl_up(inc, (unsigned)s);
        if (lane >= s) inc += u;
    }
    int base = 0;
    if (lane == 63) base = atomicAdd(total, inc);
    base = __shfl(base, 63);
    if (i < n) { int st = base + inc - c; start[i] = st; cur[i] = st; }
}

__global__ void fill_kernel(const int* __restrict__ src, const int* __restrict__ dst,
                            int* __restrict__ cur, int* __restrict__ bucket, int E) {
    int e = blockIdx.x * blockDim.x + threadIdx.x;
    if (e < E) {
        int p = atomicAdd(&cur[dst[e]], 1);
        bucket[p] = src[e];
    }
}

// ---------------- gather: z = xh + segment_sum(xh[src]) -> bf16 ----------------
// quarter-wave per node; SOFTWARE-PIPELINED: chunk n+1's 8 row-loads are issued
// BEFORE consuming chunk n, so ~8 loads stay in flight continuously instead of
// issue-8/drain-8 (T14 issue-early pattern).
__global__ __launch_bounds__(256, 4)
void gather_kernel(const u16x8* __restrict__ xh8,
                   const int* __restrict__ start, const int* __restrict__ cnt,
                   const int* __restrict__ bucket,
                   u16x8* __restrict__ z8, int n) {
    int node = blockIdx.x * 16 + (threadIdx.x >> 4);
    int lane = threadIdx.x & 15;
    if (node >= n) return;
    int e = start[node];
    int eend = e + cnt[node];
    float a[8];
    #pragma unroll
    for (int j = 0; j < 8; ++j) a[j] = 0.f;

    if (eend - e >= 8) {
        int s0 = bucket[e],     s1 = bucket[e + 1], s2 = bucket[e + 2], s3 = bucket[e + 3];
        int s4 = bucket[e + 4], s5 = bucket[e + 5], s6 = bucket[e + 6], s7 = bucket[e + 7];
        u16x8 c0 = xh8[(size_t)s0 * 16 + lane];
        u16x8 c1 = xh8[(size_t)s1 * 16 + lane];
        u16x8 c2 = xh8[(size_t)s2 * 16 + lane];
        u16x8 c3 = xh8[(size_t)s3 * 16 + lane];
        u16x8 c4 = xh8[(size_t)s4 * 16 + lane];
        u16x8 c5 = xh8[(size_t)s5 * 16 + lane];
        u16x8 c6 = xh8[(size_t)s6 * 16 + lane];
        u16x8 c7 = xh8[(size_t)s7 * 16 + lane];
        e += 8;
        for (; e + 8 <= eend; e += 8) {
            int t0 = bucket[e],     t1 = bucket[e + 1], t2 = bucket[e + 2], t3 = bucket[e + 3];
            int t4 = bucket[e + 4], t5 = bucket[e + 5], t6 = bucket[e + 6], t7 = bucket[e + 7];
            u16x8 p0 = xh8[(size_t)t0 * 16 + lane];
            u16x8 p1 = xh8[(size_t)t1 * 16 + lane];
            u16x8 p2 = xh8[(size_t)t2 * 16 + lane];
            u16x8 p3 = xh8[(size_t)t3 * 16 + lane];
            u16x8 p4 = xh8[(size_t)t4 * 16 + lane];
            u16x8 p5 = xh8[(size_t)t5 * 16 + lane];
            u16x8 p6 = xh8[(size_t)t6 * 16 + lane];
            u16x8 p7 = xh8[(size_t)t7 * 16 + lane];
            #pragma unroll
            for (int j = 0; j < 8; ++j) {
                a[j] += bf2f(c0[j]) + bf2f(c1[j]) + bf2f(c2[j]) + bf2f(c3[j])
                      + bf2f(c4[j]) + bf2f(c5[j]) + bf2f(c6[j]) + bf2f(c7[j]);
            }
            c0 = p0; c1 = p1; c2 = p2; c3 = p3;
            c4 = p4; c5 = p5; c6 = p6; c7 = p7;
        }
        #pragma unroll
        for (int j = 0; j < 8; ++j) {
            a[j] += bf2f(c0[j]) + bf2f(c1[j]) + bf2f(c2[j]) + bf2f(c3[j])
                  + bf2f(c4[j]) + bf2f(c5[j]) + bf2f(c6[j]) + bf2f(c7[j]);
        }
    }
    for (; e < eend; ++e) {
        int s = bucket[e];
        u16x8 v = xh8[(size_t)s * 16 + lane];
        #pragma unroll
        for (int j = 0; j < 8; ++j) a[j] += bf2f(v[j]);
    }
    u16x8 xv = xh8[(size_t)node * 16 + lane];
    u16x8 zo;
    #pragma unroll
    for (int j = 0; j < 8; ++j) zo[j] = f2bf(a[j] + bf2f(xv[j]));
    z8[(size_t)node * 16 + lane] = zo;
}

// ---------------- fused MLP: out = relu(z@W1+b1)@W2 + b2 (fp32) + BN stats ----------------
// Block = 4 waves = 4 tiles/iter; reg-W both layers; h1 in 16KB swizzled LDS.
// Phase 1 now prefetches ALL 16 A-fragments before any MFMA (R11 batch pattern).
__global__ __launch_bounds__(256, 3)
void fused_mlp(const ushort* __restrict__ Z, const ushort* __restrict__ wp,
               const float* __restrict__ b1, const float* __restrict__ b2,
               float* __restrict__ out, float* __restrict__ stats, int nTiles) {
    __shared__ ushort h1s[4][2048];   // 4 tiles x (16 rows x 128 cols bf16)
    int wave = threadIdx.x >> 6, lane = threadIdx.x & 63;
    int rsel = lane & 15;
    int csel = lane >> 4;
    int nf0 = wave * 2;
    const ushort* w1p = wp;
    const ushort* w2p = wp + 16384;
    s16x8 w10[4], w11[4], w20[4], w21[4];
    #pragma unroll
    for (int ks = 0; ks < 4; ++ks) {
        w10[ks] = *(const s16x8*)(w1p + ((ks * 8 + nf0) * 64 + lane) * 8);
        w11[ks] = *(const s16x8*)(w1p + ((ks * 8 + nf0 + 1) * 64 + lane) * 8);
        w20[ks] = *(const s16x8*)(w2p + ((ks * 8 + nf0) * 64 + lane) * 8);
        w21[ks] = *(const s16x8*)(w2p + ((ks * 8 + nf0 + 1) * 64 + lane) * 8);
    }
    float b10 = b1[nf0 * 16 + rsel], b11 = b1[(nf0 + 1) * 16 + rsel];
    float b20 = b2[nf0 * 16 + rsel], b21 = b2[(nf0 + 1) * 16 + rsel];
    float s0 = 0.f, q0 = 0.f, s1 = 0.f, q1 = 0.f;
    int col0 = nf0 * 16 + rsel;

    for (int t0 = blockIdx.x * 4; t0 < nTiles; t0 += gridDim.x * 4) {
        __syncthreads();   // LDS free from previous iteration
        // ---- phase 1: prefetch all 16 A-frags, then compute h1 -> LDS ----
        s16x8 A[4][4];
        #pragma unroll
        for (int t = 0; t < 4; ++t) {
            if (t0 + t < nTiles) {
                const ushort* aP = Z + ((size_t)(t0 + t) * 16 + rsel) * D + csel * 8;
                A[t][0] = *(const s16x8*)(aP);
                A[t][1] = *(const s16x8*)(aP + 32);
                A[t][2] = *(const s16x8*)(aP + 64);
                A[t][3] = *(const s16x8*)(aP + 96);
            }
        }
        #pragma unroll
        for (int t = 0; t < 4; ++t) {
            if (t0 + t < nTiles) {
                f32x4 acc0 = (f32x4){0.f, 0.f, 0.f, 0.f};
                f32x4 acc1 = (f32x4){0.f, 0.f, 0.f, 0.f};
                #pragma unroll
                for (int ks = 0; ks < 4; ++ks) {
                    acc0 = __builtin_amdgcn_mfma_f32_16x16x32_bf16(A[t][ks], w10[ks], acc0, 0, 0, 0);
                    acc1 = __builtin_amdgcn_mfma_f32_16x16x32_bf16(A[t][ks], w11[ks], acc1, 0, 0, 0);
                }
                char* tb = (char*)h1s[t];
                int c20 = col0 * 2, c21 = (col0 + 16) * 2;
                #pragma unroll
                for (int r = 0; r < 4; ++r) {
                    int rr = csel * 4 + r;
                    int sw = (rr & 7) << 4;
                    *(ushort*)(tb + rr * 256 + (c20 ^ sw)) = f2bf(fmaxf(acc0[r] + b10, 0.f));
                    *(ushort*)(tb + rr * 256 + (c21 ^ sw)) = f2bf(fmaxf(acc1[r] + b11, 0.f));
                }
            }
        }
        __syncthreads();
        // ---- phase 2: gemm2 from LDS h1 ----
        #pragma unroll
        for (int t = 0; t < 4; ++t) {
            int tile = t0 + t;
            if (tile < nTiles) {
                const char* tb = (const char*)h1s[t];
                int sw = (rsel & 7) << 4;
                s16x8 a0 = *(const s16x8*)(tb + rsel * 256 + ((csel * 16) ^ sw));
                s16x8 a1 = *(const s16x8*)(tb + rsel * 256 + ((64 + csel * 16) ^ sw));
                s16x8 a2 = *(const s16x8*)(tb + rsel * 256 + ((128 + csel * 16) ^ sw));
                s16x8 a3 = *(const s16x8*)(tb + rsel * 256 + ((192 + csel * 16) ^ sw));
                f32x4 acc0 = (f32x4){0.f, 0.f, 0.f, 0.f};
                f32x4 acc1 = (f32x4){0.f, 0.f, 0.f, 0.f};
                acc0 = __builtin_amdgcn_mfma_f32_16x16x32_bf16(a0, w20[0], acc0, 0, 0, 0);
                acc1 = __builtin_amdgcn_mfma_f32_16x16x32_bf16(a0, w21[0], acc1, 0, 0, 0);
                acc0 = __builtin_amdgcn_mfma_f32_16x16x32_bf16(a1, w20[1], acc0, 0, 0, 0);
                acc1 = __builtin_amdgcn_mfma_f32_16x16x32_bf16(a1, w21[1], acc1, 0, 0, 0);
                acc0 = __builtin_amdgcn_mfma_f32_16x16x32_bf16(a2, w20[2], acc0, 0, 0, 0);
                acc1 = __builtin_amdgcn_mfma_f32_16x16x32_bf16(a2, w21[2], acc1, 0, 0, 0);
                acc0 = __builtin_amdgcn_mfma_f32_16x16x32_bf16(a3, w20[3], acc0, 0, 0, 0);
                acc1 = __builtin_amdgcn_mfma_f32_16x16x32_bf16(a3, w21[3], acc1, 0, 0, 0);
                int orow = tile * 16 + csel * 4;
                #pragma unroll
                for (int r = 0; r < 4; ++r) {
                    float v0 = acc0[r] + b20;
                    float v1 = acc1[r] + b21;
                    out[(size_t)(orow + r) * D + col0]      = v0;
                    out[(size_t)(orow + r) * D + col0 + 16] = v1;
                    s0 += v0; q0 += v0 * v0;
                    s1 += v1; q1 += v1 * v1;
                }
            }
        }
    }
    // ---- flush stats ----
    s0 += __shfl_xor(s0, 16); s0 += __shfl_xor(s0, 32);
    q0 += __shfl_xor(q0, 16); q0 += __shfl_xor(q0, 32);
    s1 += __shfl_xor(s1, 16); s1 += __shfl_xor(s1, 32);
    q1 += __shfl_xor(q1, 16); q1 += __shfl_xor(q1, 32);
    if (csel == 0) {
        atomicAdd(&stats[col0], s0);
        atomicAdd(&stats[128 + col0], q0);
        atomicAdd(&stats[col0 + 16], s1);
        atomicAdd(&stats[128 + col0 + 16], q1);
    }
}

// ---------------- BN normalize + residual ----------------
__global__ void bn_final(float4* __restrict__ out4, const float4* __restrict__ x4,
                         const float* __restrict__ stats, const float* __restrict__ gamma,
                         const float* __restrict__ beta, int n4, float invN) {
    int i = blockIdx.x * blockDim.x + threadIdx.x;
    if (i >= n4) return;
    int cc = i & 31;
    const float4* s4 = (const float4*)stats;
    float4 sum = s4[cc], sq = s4[32 + cc];
    float4 g = ((const float4*)gamma)[cc], b = ((const float4*)beta)[cc];
    float4 h = out4[i], xx = x4[i];
    float4 o;
    {
        float m = sum.x * invN, v = sq.x * invN - m * m, iv = rsqrtf(v + 1e-5f);
        o.x = (h.x - m) * iv * g.x + b.x + xx.x;
    }
    {
        float m = sum.y * invN, v = sq.y * invN - m * m, iv = rsqrtf(v + 1e-5f);
        o.y = (h.y - m) * iv * g.y + b.y + xx.y;
    }
    {
        float m = sum.z * invN, v = sq.z * invN - m * m, iv = rsqrtf(v + 1e-5f);
        o.z = (h.z - m) * iv * g.z + b.z + xx.z;
    }
    {
        float m = sum.w * invN, v = sq.w * invN - m * m, iv = rsqrtf(v + 1e-5f);
        o.w = (h.w - m) * iv * g.w + b.w + xx.w;
    }
    out4[i] = o;
}

extern "C" void kernel_launch(void* const* d_in, const int* in_sizes, int n_in,
                              void* d_out, int out_size, void* d_ws, size_t ws_size,
                              hipStream_t stream) {
    const float* x     = (const float*)d_in[0];
    const int*   ei    = (const int*)d_in[1];
    const float* W1    = (const float*)d_in[2];
    const float* b1    = (const float*)d_in[3];
    const float* W2    = (const float*)d_in[4];
    const float* b2    = (const float*)d_in[5];
    const float* gamma = (const float*)d_in[6];
    const float* beta  = (const float*)d_in[7];
    float* out = (float*)d_out;

    int N = in_sizes[0] / D;   // 50000
    int E = in_sizes[1] / 2;   // 600000
    const int* src = ei;
    const int* dst = ei + E;

    size_t NB = (size_t)N * D;
    ushort* xh   = (ushort*)d_ws;          // NB ushorts
    ushort* z    = xh + NB;                // NB ushorts
    ushort* wp   = z + NB;                 // 2*16384
    float*  stats = (float*)(wp + 32768);  // 256 floats (16B aligned)
    int*    cnt  = (int*)(stats + 256);    // N
    int*    tot  = cnt + N;                // 1
    int*    startA = tot + 1;              // N
    int*    cur  = startA + N;             // N
    int*    bucket = cur + N;              // E

    hipMemsetAsync(stats, 0, (size_t)(256 + N + 1) * sizeof(int), stream);

    const int B = 256;
    int n4 = (int)(NB / 4);
    prep_kernel<<<2048, B, 0, stream>>>((const float4*)x, (ushort4*)xh, n4,
                                        dst, cnt, E, W1, W2, wp);
    alloc_kernel<<<(N + B - 1) / B, B, 0, stream>>>(cnt, startA, cur, tot, N);
    fill_kernel<<<(E + B - 1) / B, B, 0, stream>>>(src, dst, cur, bucket, E);
    gather_kernel<<<(N + 15) / 16, B, 0, stream>>>((const u16x8*)xh, startA, cnt, bucket,
                                                   (u16x8*)z, N);
    int nTiles = (N + 15) / 16;   // 3125
    fused_mlp<<<782, B, 0, stream>>>(z, wp, b1, b2, out, stats, nTiles);
    bn_final<<<(n4 + B - 1) / B, B, 0, stream>>>((float4*)out, (const float4*)x, stats,
                                                 gamma, beta, n4, 1.0f / (float)N);
}

// Round 14
// 150.703 us; speedup vs baseline: 1.0483x; 1.0483x over previous
//
#include <hip/hip_runtime.h>

#define D 128

typedef short s16x8 __attribute__((ext_vector_type(8)));
typedef ushort u16x8 __attribute__((ext_vector_type(8)));
typedef float f32x4 __attribute__((ext_vector_type(4)));

static __device__ __forceinline__ float bf2f(ushort h) {
    return __uint_as_float(((uint)h) << 16);
}
static __device__ __forceinline__ ushort f2bf(float f) {
    uint u = __float_as_uint(f);
    u += 0x7fffu + ((u >> 16) & 1u);   // RNE
    return (ushort)(u >> 16);
}

// ---------------- prep: x->bf16  +  degree count  +  W pack ----------------
__global__ void prep_kernel(const float4* __restrict__ x4, ushort4* __restrict__ xh4, int n4,
                            const int* __restrict__ dst, int* __restrict__ cnt, int E,
                            const float* __restrict__ W1, const float* __restrict__ W2,
                            ushort* __restrict__ wp) {
    int tid = blockIdx.x * blockDim.x + threadIdx.x;
    int stride = gridDim.x * blockDim.x;
    for (int i = tid; i < n4; i += stride) {
        float4 v = x4[i];
        ushort4 h;
        h.x = f2bf(v.x); h.y = f2bf(v.y); h.z = f2bf(v.z); h.w = f2bf(v.w);
        xh4[i] = h;
    }
    for (int e = tid; e < E; e += stride) atomicAdd(&cnt[dst[e]], 1);
    if (tid < 4096) {
        int m = tid >> 11;
        int r = tid & 2047;
        int lane = r & 63;
        int nf = (r >> 6) & 7;
        int ks = r >> 9;
        const float* W = m ? W2 : W1;
        ushort* o = wp + m * 16384;
        int k0 = ks * 32 + ((lane >> 4) << 3);
        int c = nf * 16 + (lane & 15);
        #pragma unroll
        for (int i = 0; i < 8; ++i) o[r * 8 + i] = f2bf(W[(k0 + i) * D + c]);
    }
}

// ---------------- CSR alloc + fill ----------------
__global__ void alloc_kernel(const int* __restrict__ cnt, int* __restrict__ start,
                             int* __restrict__ cur, int* __restrict__ total, int n) {
    int i = blockIdx.x * blockDim.x + threadIdx.x;
    int lane = threadIdx.x & 63;
    int c = (i < n) ? cnt[i] : 0;
    int inc = c;
    #pragma unroll
    for (int s = 1; s < 64; s <<= 1) {
        int u = __shfl_up(inc, (unsigned)s);
        if (lane >= s) inc += u;
    }
    int base = 0;
    if (lane == 63) base = atomicAdd(total, inc);
    base = __shfl(base, 63);
    if (i < n) { int st = base + inc - c; start[i] = st; cur[i] = st; }
}

__global__ void fill_kernel(const int* __restrict__ src, const int* __restrict__ dst,
                            int* __restrict__ cur, int* __restrict__ bucket, int E) {
    int e = blockIdx.x * blockDim.x + threadIdx.x;
    if (e < E) {
        int p = atomicAdd(&cur[dst[e]], 1);
        bucket[p] = src[e];
    }
}

// ---------------- gather: z = xh + segment_sum(xh[src]) -> bf16 ----------------
// quarter-wave (16 lanes x 16B) per node; BW-bound at this occupancy (R13's
// latency-pipeline was null) -> keep the simple R12 form.
__global__ void gather_kernel(const u16x8* __restrict__ xh8,
                              const int* __restrict__ start, const int* __restrict__ cnt,
                              const int* __restrict__ bucket,
                              u16x8* __restrict__ z8, int n) {
    int node = blockIdx.x * 16 + (threadIdx.x >> 4);
    int lane = threadIdx.x & 15;
    if (node >= n) return;
    int e0 = start[node];
    int eend = e0 + cnt[node];
    float a[8];
    #pragma unroll
    for (int j = 0; j < 8; ++j) a[j] = 0.f;
    int e = e0;
    for (; e + 8 <= eend; e += 8) {
        int s0 = bucket[e],     s1 = bucket[e + 1], s2 = bucket[e + 2], s3 = bucket[e + 3];
        int s4 = bucket[e + 4], s5 = bucket[e + 5], s6 = bucket[e + 6], s7 = bucket[e + 7];
        u16x8 v0 = xh8[(size_t)s0 * 16 + lane];
        u16x8 v1 = xh8[(size_t)s1 * 16 + lane];
        u16x8 v2 = xh8[(size_t)s2 * 16 + lane];
        u16x8 v3 = xh8[(size_t)s3 * 16 + lane];
        u16x8 v4 = xh8[(size_t)s4 * 16 + lane];
        u16x8 v5 = xh8[(size_t)s5 * 16 + lane];
        u16x8 v6 = xh8[(size_t)s6 * 16 + lane];
        u16x8 v7 = xh8[(size_t)s7 * 16 + lane];
        #pragma unroll
        for (int j = 0; j < 8; ++j) {
            a[j] += bf2f(v0[j]) + bf2f(v1[j]) + bf2f(v2[j]) + bf2f(v3[j])
                  + bf2f(v4[j]) + bf2f(v5[j]) + bf2f(v6[j]) + bf2f(v7[j]);
        }
    }
    for (; e + 4 <= eend; e += 4) {
        int s0 = bucket[e], s1 = bucket[e + 1], s2 = bucket[e + 2], s3 = bucket[e + 3];
        u16x8 v0 = xh8[(size_t)s0 * 16 + lane];
        u16x8 v1 = xh8[(size_t)s1 * 16 + lane];
        u16x8 v2 = xh8[(size_t)s2 * 16 + lane];
        u16x8 v3 = xh8[(size_t)s3 * 16 + lane];
        #pragma unroll
        for (int j = 0; j < 8; ++j)
            a[j] += bf2f(v0[j]) + bf2f(v1[j]) + bf2f(v2[j]) + bf2f(v3[j]);
    }
    for (; e < eend; ++e) {
        int s = bucket[e];
        u16x8 v = xh8[(size_t)s * 16 + lane];
        #pragma unroll
        for (int j = 0; j < 8; ++j) a[j] += bf2f(v[j]);
    }
    u16x8 xv = xh8[(size_t)node * 16 + lane];
    u16x8 zo;
    #pragma unroll
    for (int j = 0; j < 8; ++j) zo[j] = f2bf(a[j] + bf2f(xv[j]));
    z8[(size_t)node * 16 + lane] = zo;
}

// ---------------- fused MLP: h2 = relu(z@W1+b1)@W2 + b2 -> bf16, + BN stats ----------------
// Block = 4 waves = 4 tiles/iter; reg-W both layers; h1 in 16KB swizzled LDS
// (R12's proven structure). h2 now stored as bf16 (halves the write traffic);
// stats still accumulated from fp32 accumulators.
__global__ __launch_bounds__(256, 3)
void fused_mlp(const ushort* __restrict__ Z, const ushort* __restrict__ wp,
               const float* __restrict__ b1, const float* __restrict__ b2,
               ushort* __restrict__ H2, float* __restrict__ stats, int nTiles) {
    __shared__ ushort h1s[4][2048];   // 4 tiles x (16 rows x 128 cols bf16)
    int wave = threadIdx.x >> 6, lane = threadIdx.x & 63;
    int rsel = lane & 15;
    int csel = lane >> 4;
    int nf0 = wave * 2;
    const ushort* w1p = wp;
    const ushort* w2p = wp + 16384;
    s16x8 w10[4], w11[4], w20[4], w21[4];
    #pragma unroll
    for (int ks = 0; ks < 4; ++ks) {
        w10[ks] = *(const s16x8*)(w1p + ((ks * 8 + nf0) * 64 + lane) * 8);
        w11[ks] = *(const s16x8*)(w1p + ((ks * 8 + nf0 + 1) * 64 + lane) * 8);
        w20[ks] = *(const s16x8*)(w2p + ((ks * 8 + nf0) * 64 + lane) * 8);
        w21[ks] = *(const s16x8*)(w2p + ((ks * 8 + nf0 + 1) * 64 + lane) * 8);
    }
    float b10 = b1[nf0 * 16 + rsel], b11 = b1[(nf0 + 1) * 16 + rsel];
    float b20 = b2[nf0 * 16 + rsel], b21 = b2[(nf0 + 1) * 16 + rsel];
    float s0 = 0.f, q0 = 0.f, s1 = 0.f, q1 = 0.f;
    int col0 = nf0 * 16 + rsel;

    for (int t0 = blockIdx.x * 4; t0 < nTiles; t0 += gridDim.x * 4) {
        __syncthreads();   // LDS free from previous iteration
        // ---- phase 1: h1 tiles -> LDS (each wave: its 32 cols of all 4 tiles) ----
        #pragma unroll
        for (int t = 0; t < 4; ++t) {
            int tile = t0 + t;
            if (tile < nTiles) {
                const ushort* aP = Z + ((size_t)tile * 16 + rsel) * D + csel * 8;
                s16x8 a0 = *(const s16x8*)(aP);
                s16x8 a1 = *(const s16x8*)(aP + 32);
                s16x8 a2 = *(const s16x8*)(aP + 64);
                s16x8 a3 = *(const s16x8*)(aP + 96);
                f32x4 acc0 = (f32x4){0.f, 0.f, 0.f, 0.f};
                f32x4 acc1 = (f32x4){0.f, 0.f, 0.f, 0.f};
                acc0 = __builtin_amdgcn_mfma_f32_16x16x32_bf16(a0, w10[0], acc0, 0, 0, 0);
                acc1 = __builtin_amdgcn_mfma_f32_16x16x32_bf16(a0, w11[0], acc1, 0, 0, 0);
                acc0 = __builtin_amdgcn_mfma_f32_16x16x32_bf16(a1, w10[1], acc0, 0, 0, 0);
                acc1 = __builtin_amdgcn_mfma_f32_16x16x32_bf16(a1, w11[1], acc1, 0, 0, 0);
                acc0 = __builtin_amdgcn_mfma_f32_16x16x32_bf16(a2, w10[2], acc0, 0, 0, 0);
                acc1 = __builtin_amdgcn_mfma_f32_16x16x32_bf16(a2, w11[2], acc1, 0, 0, 0);
                acc0 = __builtin_amdgcn_mfma_f32_16x16x32_bf16(a3, w10[3], acc0, 0, 0, 0);
                acc1 = __builtin_amdgcn_mfma_f32_16x16x32_bf16(a3, w11[3], acc1, 0, 0, 0);
                char* tb = (char*)h1s[t];
                int c20 = col0 * 2, c21 = (col0 + 16) * 2;
                #pragma unroll
                for (int r = 0; r < 4; ++r) {
                    int rr = csel * 4 + r;
                    int sw = (rr & 7) << 4;
                    *(ushort*)(tb + rr * 256 + (c20 ^ sw)) = f2bf(fmaxf(acc0[r] + b10, 0.f));
                    *(ushort*)(tb + rr * 256 + (c21 ^ sw)) = f2bf(fmaxf(acc1[r] + b11, 0.f));
                }
            }
        }
        __syncthreads();
        // ---- phase 2: gemm2 from LDS h1, h2 -> bf16 global + reg stats ----
        #pragma unroll
        for (int t = 0; t < 4; ++t) {
            int tile = t0 + t;
            if (tile < nTiles) {
                const char* tb = (const char*)h1s[t];
                int sw = (rsel & 7) << 4;
                s16x8 a0 = *(const s16x8*)(tb + rsel * 256 + ((csel * 16) ^ sw));
                s16x8 a1 = *(const s16x8*)(tb + rsel * 256 + ((64 + csel * 16) ^ sw));
                s16x8 a2 = *(const s16x8*)(tb + rsel * 256 + ((128 + csel * 16) ^ sw));
                s16x8 a3 = *(const s16x8*)(tb + rsel * 256 + ((192 + csel * 16) ^ sw));
                f32x4 acc0 = (f32x4){0.f, 0.f, 0.f, 0.f};
                f32x4 acc1 = (f32x4){0.f, 0.f, 0.f, 0.f};
                acc0 = __builtin_amdgcn_mfma_f32_16x16x32_bf16(a0, w20[0], acc0, 0, 0, 0);
                acc1 = __builtin_amdgcn_mfma_f32_16x16x32_bf16(a0, w21[0], acc1, 0, 0, 0);
                acc0 = __builtin_amdgcn_mfma_f32_16x16x32_bf16(a1, w20[1], acc0, 0, 0, 0);
                acc1 = __builtin_amdgcn_mfma_f32_16x16x32_bf16(a1, w21[1], acc1, 0, 0, 0);
                acc0 = __builtin_amdgcn_mfma_f32_16x16x32_bf16(a2, w20[2], acc0, 0, 0, 0);
                acc1 = __builtin_amdgcn_mfma_f32_16x16x32_bf16(a2, w21[2], acc1, 0, 0, 0);
                acc0 = __builtin_amdgcn_mfma_f32_16x16x32_bf16(a3, w20[3], acc0, 0, 0, 0);
                acc1 = __builtin_amdgcn_mfma_f32_16x16x32_bf16(a3, w21[3], acc1, 0, 0, 0);
                int orow = tile * 16 + csel * 4;
                #pragma unroll
                for (int r = 0; r < 4; ++r) {
                    float v0 = acc0[r] + b20;
                    float v1 = acc1[r] + b21;
                    H2[(size_t)(orow + r) * D + col0]      = f2bf(v0);
                    H2[(size_t)(orow + r) * D + col0 + 16] = f2bf(v1);
                    s0 += v0; q0 += v0 * v0;
                    s1 += v1; q1 += v1 * v1;
                }
            }
        }
    }
    // ---- flush stats ----
    s0 += __shfl_xor(s0, 16); s0 += __shfl_xor(s0, 32);
    q0 += __shfl_xor(q0, 16); q0 += __shfl_xor(q0, 32);
    s1 += __shfl_xor(s1, 16); s1 += __shfl_xor(s1, 32);
    q1 += __shfl_xor(q1, 16); q1 += __shfl_xor(q1, 32);
    if (csel == 0) {
        atomicAdd(&stats[col0], s0);
        atomicAdd(&stats[128 + col0], q0);
        atomicAdd(&stats[col0 + 16], s1);
        atomicAdd(&stats[128 + col0 + 16], q1);
    }
}

// ---------------- BN normalize + residual (bf16 h2 + bf16 x -> fp32 out) ----------------
__global__ void bn_final(const u16x8* __restrict__ h8, const u16x8* __restrict__ xh8,
                         float* __restrict__ out,
                         const float* __restrict__ stats, const float* __restrict__ gamma,
                         const float* __restrict__ beta, int n8, float invN) {
    int i = blockIdx.x * blockDim.x + threadIdx.x;
    if (i >= n8) return;
    int cg = (i & 15) * 8;   // channel base for this ushort8
    u16x8 hv = h8[i];
    u16x8 xv = xh8[i];
    float o[8];
    #pragma unroll
    for (int j = 0; j < 8; ++j) {
        int c = cg + j;
        float m = stats[c] * invN;
        float var = stats[128 + c] * invN - m * m;
        float iv = rsqrtf(var + 1e-5f);
        o[j] = (bf2f(hv[j]) - m) * iv * gamma[c] + beta[c] + bf2f(xv[j]);
    }
    float4* o4 = (float4*)(out + (size_t)i * 8);
    o4[0] = make_float4(o[0], o[1], o[2], o[3]);
    o4[1] = make_float4(o[4], o[5], o[6], o[7]);
}

extern "C" void kernel_launch(void* const* d_in, const int* in_sizes, int n_in,
                              void* d_out, int out_size, void* d_ws, size_t ws_size,
                              hipStream_t stream) {
    const float* x     = (const float*)d_in[0];
    const int*   ei    = (const int*)d_in[1];
    const float* W1    = (const float*)d_in[2];
    const float* b1    = (const float*)d_in[3];
    const float* W2    = (const float*)d_in[4];
    const float* b2    = (const float*)d_in[5];
    const float* gamma = (const float*)d_in[6];
    const float* beta  = (const float*)d_in[7];
    float* out = (float*)d_out;

    int N = in_sizes[0] / D;   // 50000
    int E = in_sizes[1] / 2;   // 600000
    const int* src = ei;
    const int* dst = ei + E;

    size_t NB = (size_t)N * D;
    ushort* xh   = (ushort*)d_ws;          // NB ushorts
    ushort* z    = xh + NB;                // NB ushorts
    ushort* h2   = z + NB;                 // NB ushorts
    ushort* wp   = h2 + NB;                // 2*16384
    float*  stats = (float*)(wp + 32768);  // 256 floats (16B aligned)
    int*    cnt  = (int*)(stats + 256);    // N
    int*    tot  = cnt + N;                // 1
    int*    startA = tot + 1;              // N
    int*    cur  = startA + N;             // N
    int*    bucket = cur + N;              // E

    hipMemsetAsync(stats, 0, (size_t)(256 + N + 1) * sizeof(int), stream);

    const int B = 256;
    int n4 = (int)(NB / 4);
    prep_kernel<<<2048, B, 0, stream>>>((const float4*)x, (ushort4*)xh, n4,
                                        dst, cnt, E, W1, W2, wp);
    alloc_kernel<<<(N + B - 1) / B, B, 0, stream>>>(cnt, startA, cur, tot, N);
    fill_kernel<<<(E + B - 1) / B, B, 0, stream>>>(src, dst, cur, bucket, E);
    gather_kernel<<<(N + 15) / 16, B, 0, stream>>>((const u16x8*)xh, startA, cnt, bucket,
                                                   (u16x8*)z, N);
    int nTiles = (N + 15) / 16;   // 3125
    fused_mlp<<<782, B, 0, stream>>>(z, wp, b1, b2, h2, stats, nTiles);
    int n8 = (int)(NB / 8);
    bn_final<<<(n8 + B - 1) / B, B, 0, stream>>>((const u16x8*)h2, (const u16x8*)xh,
                                                 out, stats, gamma, beta, n8,
                                                 1.0f / (float)N);
}

// Round 15
// 148.596 us; speedup vs baseline: 1.0631x; 1.0142x over previous
//
#include <hip/hip_runtime.h>

#define D 128

typedef short s16x8 __attribute__((ext_vector_type(8)));
typedef ushort u16x8 __attribute__((ext_vector_type(8)));
typedef float f32x4 __attribute__((ext_vector_type(4)));

static __device__ __forceinline__ float bf2f(ushort h) {
    return __uint_as_float(((uint)h) << 16);
}
static __device__ __forceinline__ ushort f2bf(float f) {
    uint u = __float_as_uint(f);
    u += 0x7fffu + ((u >> 16) & 1u);   // RNE
    return (ushort)(u >> 16);
}

// ---------------- zero scratch (replaces pathological 41us rocclr fill) ----------------
__global__ void zero_kernel(int* __restrict__ p, int n) {
    int i = blockIdx.x * blockDim.x + threadIdx.x;
    if (i < n) p[i] = 0;
}

// ---------------- prep: x->bf16  +  degree count  +  W pack ----------------
__global__ void prep_kernel(const float4* __restrict__ x4, ushort4* __restrict__ xh4, int n4,
                            const int* __restrict__ dst, int* __restrict__ cnt, int E,
                            const float* __restrict__ W1, const float* __restrict__ W2,
                            ushort* __restrict__ wp) {
    int tid = blockIdx.x * blockDim.x + threadIdx.x;
    int stride = gridDim.x * blockDim.x;
    for (int i = tid; i < n4; i += stride) {
        float4 v = x4[i];
        ushort4 h;
        h.x = f2bf(v.x); h.y = f2bf(v.y); h.z = f2bf(v.z); h.w = f2bf(v.w);
        xh4[i] = h;
    }
    for (int e = tid; e < E; e += stride) atomicAdd(&cnt[dst[e]], 1);
    if (tid < 4096) {
        int m = tid >> 11;
        int r = tid & 2047;
        int lane = r & 63;
        int nf = (r >> 6) & 7;
        int ks = r >> 9;
        const float* W = m ? W2 : W1;
        ushort* o = wp + m * 16384;
        int k0 = ks * 32 + ((lane >> 4) << 3);
        int c = nf * 16 + (lane & 15);
        #pragma unroll
        for (int i = 0; i < 8; ++i) o[r * 8 + i] = f2bf(W[(k0 + i) * D + c]);
    }
}

// ---------------- CSR alloc + fill ----------------
__global__ void alloc_kernel(const int* __restrict__ cnt, int* __restrict__ start,
                             int* __restrict__ cur, int* __restrict__ total, int n) {
    int i = blockIdx.x * blockDim.x + threadIdx.x;
    int lane = threadIdx.x & 63;
    int c = (i < n) ? cnt[i] : 0;
    int inc = c;
    #pragma unroll
    for (int s = 1; s < 64; s <<= 1) {
        int u = __shfl_up(inc, (unsigned)s);
        if (lane >= s) inc += u;
    }
    int base = 0;
    if (lane == 63) base = atomicAdd(total, inc);
    base = __shfl(base, 63);
    if (i < n) { int st = base + inc - c; start[i] = st; cur[i] = st; }
}

__global__ void fill_kernel(const int* __restrict__ src, const int* __restrict__ dst,
                            int* __restrict__ cur, int* __restrict__ bucket, int E) {
    int e = blockIdx.x * blockDim.x + threadIdx.x;
    if (e < E) {
        int p = atomicAdd(&cur[dst[e]], 1);
        bucket[p] = src[e];
    }
}

// ---------------- gather: z = xh + segment_sum(xh[src]) -> bf16 ----------------
__global__ void gather_kernel(const u16x8* __restrict__ xh8,
                              const int* __restrict__ start, const int* __restrict__ cnt,
                              const int* __restrict__ bucket,
                              u16x8* __restrict__ z8, int n) {
    int node = blockIdx.x * 16 + (threadIdx.x >> 4);
    int lane = threadIdx.x & 15;
    if (node >= n) return;
    int e0 = start[node];
    int eend = e0 + cnt[node];
    float a[8];
    #pragma unroll
    for (int j = 0; j < 8; ++j) a[j] = 0.f;
    int e = e0;
    for (; e + 8 <= eend; e += 8) {
        int s0 = bucket[e],     s1 = bucket[e + 1], s2 = bucket[e + 2], s3 = bucket[e + 3];
        int s4 = bucket[e + 4], s5 = bucket[e + 5], s6 = bucket[e + 6], s7 = bucket[e + 7];
        u16x8 v0 = xh8[(size_t)s0 * 16 + lane];
        u16x8 v1 = xh8[(size_t)s1 * 16 + lane];
        u16x8 v2 = xh8[(size_t)s2 * 16 + lane];
        u16x8 v3 = xh8[(size_t)s3 * 16 + lane];
        u16x8 v4 = xh8[(size_t)s4 * 16 + lane];
        u16x8 v5 = xh8[(size_t)s5 * 16 + lane];
        u16x8 v6 = xh8[(size_t)s6 * 16 + lane];
        u16x8 v7 = xh8[(size_t)s7 * 16 + lane];
        #pragma unroll
        for (int j = 0; j < 8; ++j) {
            a[j] += bf2f(v0[j]) + bf2f(v1[j]) + bf2f(v2[j]) + bf2f(v3[j])
                  + bf2f(v4[j]) + bf2f(v5[j]) + bf2f(v6[j]) + bf2f(v7[j]);
        }
    }
    for (; e + 4 <= eend; e += 4) {
        int s0 = bucket[e], s1 = bucket[e + 1], s2 = bucket[e + 2], s3 = bucket[e + 3];
        u16x8 v0 = xh8[(size_t)s0 * 16 + lane];
        u16x8 v1 = xh8[(size_t)s1 * 16 + lane];
        u16x8 v2 = xh8[(size_t)s2 * 16 + lane];
        u16x8 v3 = xh8[(size_t)s3 * 16 + lane];
        #pragma unroll
        for (int j = 0; j < 8; ++j)
            a[j] += bf2f(v0[j]) + bf2f(v1[j]) + bf2f(v2[j]) + bf2f(v3[j]);
    }
    for (; e < eend; ++e) {
        int s = bucket[e];
        u16x8 v = xh8[(size_t)s * 16 + lane];
        #pragma unroll
        for (int j = 0; j < 8; ++j) a[j] += bf2f(v[j]);
    }
    u16x8 xv = xh8[(size_t)node * 16 + lane];
    u16x8 zo;
    #pragma unroll
    for (int j = 0; j < 8; ++j) zo[j] = f2bf(a[j] + bf2f(xv[j]));
    z8[(size_t)node * 16 + lane] = zo;
}

// ---------------- fused MLP: h2 = relu(z@W1+b1)@W2 + b2 -> bf16, + BN stats ----------------
__global__ __launch_bounds__(256, 3)
void fused_mlp(const ushort* __restrict__ Z, const ushort* __restrict__ wp,
               const float* __restrict__ b1, const float* __restrict__ b2,
               ushort* __restrict__ H2, float* __restrict__ stats, int nTiles) {
    __shared__ ushort h1s[4][2048];   // 4 tiles x (16 rows x 128 cols bf16)
    int wave = threadIdx.x >> 6, lane = threadIdx.x & 63;
    int rsel = lane & 15;
    int csel = lane >> 4;
    int nf0 = wave * 2;
    const ushort* w1p = wp;
    const ushort* w2p = wp + 16384;
    s16x8 w10[4], w11[4], w20[4], w21[4];
    #pragma unroll
    for (int ks = 0; ks < 4; ++ks) {
        w10[ks] = *(const s16x8*)(w1p + ((ks * 8 + nf0) * 64 + lane) * 8);
        w11[ks] = *(const s16x8*)(w1p + ((ks * 8 + nf0 + 1) * 64 + lane) * 8);
        w20[ks] = *(const s16x8*)(w2p + ((ks * 8 + nf0) * 64 + lane) * 8);
        w21[ks] = *(const s16x8*)(w2p + ((ks * 8 + nf0 + 1) * 64 + lane) * 8);
    }
    float b10 = b1[nf0 * 16 + rsel], b11 = b1[(nf0 + 1) * 16 + rsel];
    float b20 = b2[nf0 * 16 + rsel], b21 = b2[(nf0 + 1) * 16 + rsel];
    float s0 = 0.f, q0 = 0.f, s1 = 0.f, q1 = 0.f;
    int col0 = nf0 * 16 + rsel;

    for (int t0 = blockIdx.x * 4; t0 < nTiles; t0 += gridDim.x * 4) {
        __syncthreads();   // LDS free from previous iteration
        // ---- phase 1: h1 tiles -> LDS (each wave: its 32 cols of all 4 tiles) ----
        #pragma unroll
        for (int t = 0; t < 4; ++t) {
            int tile = t0 + t;
            if (tile < nTiles) {
                const ushort* aP = Z + ((size_t)tile * 16 + rsel) * D + csel * 8;
                s16x8 a0 = *(const s16x8*)(aP);
                s16x8 a1 = *(const s16x8*)(aP + 32);
                s16x8 a2 = *(const s16x8*)(aP + 64);
                s16x8 a3 = *(const s16x8*)(aP + 96);
                f32x4 acc0 = (f32x4){0.f, 0.f, 0.f, 0.f};
                f32x4 acc1 = (f32x4){0.f, 0.f, 0.f, 0.f};
                acc0 = __builtin_amdgcn_mfma_f32_16x16x32_bf16(a0, w10[0], acc0, 0, 0, 0);
                acc1 = __builtin_amdgcn_mfma_f32_16x16x32_bf16(a0, w11[0], acc1, 0, 0, 0);
                acc0 = __builtin_amdgcn_mfma_f32_16x16x32_bf16(a1, w10[1], acc0, 0, 0, 0);
                acc1 = __builtin_amdgcn_mfma_f32_16x16x32_bf16(a1, w11[1], acc1, 0, 0, 0);
                acc0 = __builtin_amdgcn_mfma_f32_16x16x32_bf16(a2, w10[2], acc0, 0, 0, 0);
                acc1 = __builtin_amdgcn_mfma_f32_16x16x32_bf16(a2, w11[2], acc1, 0, 0, 0);
                acc0 = __builtin_amdgcn_mfma_f32_16x16x32_bf16(a3, w10[3], acc0, 0, 0, 0);
                acc1 = __builtin_amdgcn_mfma_f32_16x16x32_bf16(a3, w11[3], acc1, 0, 0, 0);
                char* tb = (char*)h1s[t];
                int c20 = col0 * 2, c21 = (col0 + 16) * 2;
                #pragma unroll
                for (int r = 0; r < 4; ++r) {
                    int rr = csel * 4 + r;
                    int sw = (rr & 7) << 4;
                    *(ushort*)(tb + rr * 256 + (c20 ^ sw)) = f2bf(fmaxf(acc0[r] + b10, 0.f));
                    *(ushort*)(tb + rr * 256 + (c21 ^ sw)) = f2bf(fmaxf(acc1[r] + b11, 0.f));
                }
            }
        }
        __syncthreads();
        // ---- phase 2: gemm2 from LDS h1, h2 -> bf16 global + reg stats ----
        #pragma unroll
        for (int t = 0; t < 4; ++t) {
            int tile = t0 + t;
            if (tile < nTiles) {
                const char* tb = (const char*)h1s[t];
                int sw = (rsel & 7) << 4;
                s16x8 a0 = *(const s16x8*)(tb + rsel * 256 + ((csel * 16) ^ sw));
                s16x8 a1 = *(const s16x8*)(tb + rsel * 256 + ((64 + csel * 16) ^ sw));
                s16x8 a2 = *(const s16x8*)(tb + rsel * 256 + ((128 + csel * 16) ^ sw));
                s16x8 a3 = *(const s16x8*)(tb + rsel * 256 + ((192 + csel * 16) ^ sw));
                f32x4 acc0 = (f32x4){0.f, 0.f, 0.f, 0.f};
                f32x4 acc1 = (f32x4){0.f, 0.f, 0.f, 0.f};
                acc0 = __builtin_amdgcn_mfma_f32_16x16x32_bf16(a0, w20[0], acc0, 0, 0, 0);
                acc1 = __builtin_amdgcn_mfma_f32_16x16x32_bf16(a0, w21[0], acc1, 0, 0, 0);
                acc0 = __builtin_amdgcn_mfma_f32_16x16x32_bf16(a1, w20[1], acc0, 0, 0, 0);
                acc1 = __builtin_amdgcn_mfma_f32_16x16x32_bf16(a1, w21[1], acc1, 0, 0, 0);
                acc0 = __builtin_amdgcn_mfma_f32_16x16x32_bf16(a2, w20[2], acc0, 0, 0, 0);
                acc1 = __builtin_amdgcn_mfma_f32_16x16x32_bf16(a2, w21[2], acc1, 0, 0, 0);
                acc0 = __builtin_amdgcn_mfma_f32_16x16x32_bf16(a3, w20[3], acc0, 0, 0, 0);
                acc1 = __builtin_amdgcn_mfma_f32_16x16x32_bf16(a3, w21[3], acc1, 0, 0, 0);
                int orow = tile * 16 + csel * 4;
                #pragma unroll
                for (int r = 0; r < 4; ++r) {
                    float v0 = acc0[r] + b20;
                    float v1 = acc1[r] + b21;
                    H2[(size_t)(orow + r) * D + col0]      = f2bf(v0);
                    H2[(size_t)(orow + r) * D + col0 + 16] = f2bf(v1);
                    s0 += v0; q0 += v0 * v0;
                    s1 += v1; q1 += v1 * v1;
                }
            }
        }
    }
    // ---- flush stats ----
    s0 += __shfl_xor(s0, 16); s0 += __shfl_xor(s0, 32);
    q0 += __shfl_xor(q0, 16); q0 += __shfl_xor(q0, 32);
    s1 += __shfl_xor(s1, 16); s1 += __shfl_xor(s1, 32);
    q1 += __shfl_xor(q1, 16); q1 += __shfl_xor(q1, 32);
    if (csel == 0) {
        atomicAdd(&stats[col0], s0);
        atomicAdd(&stats[128 + col0], q0);
        atomicAdd(&stats[col0 + 16], s1);
        atomicAdd(&stats[128 + col0 + 16], q1);
    }
}

// ---------------- BN normalize + residual (bf16 h2 + bf16 x -> fp32 out) ----------------
__global__ void bn_final(const u16x8* __restrict__ h8, const u16x8* __restrict__ xh8,
                         float* __restrict__ out,
                         const float* __restrict__ stats, const float* __restrict__ gamma,
                         const float* __restrict__ beta, int n8, float invN) {
    int i = blockIdx.x * blockDim.x + threadIdx.x;
    if (i >= n8) return;
    int cg = (i & 15) * 8;   // channel base for this ushort8
    u16x8 hv = h8[i];
    u16x8 xv = xh8[i];
    float o[8];
    #pragma unroll
    for (int j = 0; j < 8; ++j) {
        int c = cg + j;
        float m = stats[c] * invN;
        float var = stats[128 + c] * invN - m * m;
        float iv = rsqrtf(var + 1e-5f);
        o[j] = (bf2f(hv[j]) - m) * iv * gamma[c] + beta[c] + bf2f(xv[j]);
    }
    float4* o4 = (float4*)(out + (size_t)i * 8);
    o4[0] = make_float4(o[0], o[1], o[2], o[3]);
    o4[1] = make_float4(o[4], o[5], o[6], o[7]);
}

extern "C" void kernel_launch(void* const* d_in, const int* in_sizes, int n_in,
                              void* d_out, int out_size, void* d_ws, size_t ws_size,
                              hipStream_t stream) {
    const float* x     = (const float*)d_in[0];
    const int*   ei    = (const int*)d_in[1];
    const float* W1    = (const float*)d_in[2];
    const float* b1    = (const float*)d_in[3];
    const float* W2    = (const float*)d_in[4];
    const float* b2    = (const float*)d_in[5];
    const float* gamma = (const float*)d_in[6];
    const float* beta  = (const float*)d_in[7];
    float* out = (float*)d_out;

    int N = in_sizes[0] / D;   // 50000
    int E = in_sizes[1] / 2;   // 600000
    const int* src = ei;
    const int* dst = ei + E;

    size_t NB = (size_t)N * D;
    ushort* xh   = (ushort*)d_ws;          // NB ushorts
    ushort* z    = xh + NB;                // NB ushorts
    ushort* h2   = z + NB;                 // NB ushorts
    ushort* wp   = h2 + NB;                // 2*16384
    float*  stats = (float*)(wp + 32768);  // 256 floats (16B aligned)
    int*    cnt  = (int*)(stats + 256);    // N
    int*    tot  = cnt + N;                // 1
    int*    startA = tot + 1;              // N
    int*    cur  = startA + N;             // N
    int*    bucket = cur + N;              // E

    const int B = 256;
    int nz = 256 + N + 1;   // stats + cnt + tot (contiguous ints)
    zero_kernel<<<(nz + B - 1) / B, B, 0, stream>>>((int*)stats, nz);

    int n4 = (int)(NB / 4);
    prep_kernel<<<2048, B, 0, stream>>>((const float4*)x, (ushort4*)xh, n4,
                                        dst, cnt, E, W1, W2, wp);
    alloc_kernel<<<(N + B - 1) / B, B, 0, stream>>>(cnt, startA, cur, tot, N);
    fill_kernel<<<(E + B - 1) / B, B, 0, stream>>>(src, dst, cur, bucket, E);
    gather_kernel<<<(N + 15) / 16, B, 0, stream>>>((const u16x8*)xh, startA, cnt, bucket,
                                                   (u16x8*)z, N);
    int nTiles = (N + 15) / 16;   // 3125
    fused_mlp<<<782, B, 0, stream>>>(z, wp, b1, b2, h2, stats, nTiles);
    int n8 = (int)(NB / 8);
    bn_final<<<(n8 + B - 1) / B, B, 0, stream>>>((const u16x8*)h2, (const u16x8*)xh,
                                                 out, stats, gamma, beta, n8,
                                                 1.0f / (float)N);
}

// Round 16
// 146.946 us; speedup vs baseline: 1.0751x; 1.0112x over previous
//
#include <hip/hip_runtime.h>

#define D 128

typedef short s16x8 __attribute__((ext_vector_type(8)));
typedef ushort u16x8 __attribute__((ext_vector_type(8)));
typedef float f32x4 __attribute__((ext_vector_type(4)));

static __device__ __forceinline__ float bf2f(ushort h) {
    return __uint_as_float(((uint)h) << 16);
}
static __device__ __forceinline__ ushort f2bf(float f) {
    uint u = __float_as_uint(f);
    u += 0x7fffu + ((u >> 16) & 1u);   // RNE
    return (ushort)(u >> 16);
}

// ---------------- zero scratch ----------------
__global__ void zero_kernel(int* __restrict__ p, int n) {
    int i = blockIdx.x * blockDim.x + threadIdx.x;
    if (i < n) p[i] = 0;
}

// ---------------- prep: x->bf16  +  degree count  +  W pack ----------------
__global__ void prep_kernel(const float4* __restrict__ x4, ushort4* __restrict__ xh4, int n4,
                            const int* __restrict__ dst, int* __restrict__ cnt, int E,
                            const float* __restrict__ W1, const float* __restrict__ W2,
                            ushort* __restrict__ wp) {
    int tid = blockIdx.x * blockDim.x + threadIdx.x;
    int stride = gridDim.x * blockDim.x;
    for (int i = tid; i < n4; i += stride) {
        float4 v = x4[i];
        ushort4 h;
        h.x = f2bf(v.x); h.y = f2bf(v.y); h.z = f2bf(v.z); h.w = f2bf(v.w);
        xh4[i] = h;
    }
    for (int e = tid; e < E; e += stride) atomicAdd(&cnt[dst[e]], 1);
    if (tid < 4096) {
        int m = tid >> 11;
        int r = tid & 2047;
        int lane = r & 63;
        int nf = (r >> 6) & 7;
        int ks = r >> 9;
        const float* W = m ? W2 : W1;
        ushort* o = wp + m * 16384;
        int k0 = ks * 32 + ((lane >> 4) << 3);
        int c = nf * 16 + (lane & 15);
        #pragma unroll
        for (int i = 0; i < 8; ++i) o[r * 8 + i] = f2bf(W[(k0 + i) * D + c]);
    }
}

// ---------------- CSR alloc + fill ----------------
__global__ void alloc_kernel(const int* __restrict__ cnt, int* __restrict__ start,
                             int* __restrict__ cur, int* __restrict__ total, int n) {
    int i = blockIdx.x * blockDim.x + threadIdx.x;
    int lane = threadIdx.x & 63;
    int c = (i < n) ? cnt[i] : 0;
    int inc = c;
    #pragma unroll
    for (int s = 1; s < 64; s <<= 1) {
        int u = __shfl_up(inc, (unsigned)s);
        if (lane >= s) inc += u;
    }
    int base = 0;
    if (lane == 63) base = atomicAdd(total, inc);
    base = __shfl(base, 63);
    if (i < n) { int st = base + inc - c; start[i] = st; cur[i] = st; }
}

// bucket is ushort: N=50000 < 65536, halves fill/gather index traffic
__global__ void fill_kernel(const int* __restrict__ src, const int* __restrict__ dst,
                            int* __restrict__ cur, ushort* __restrict__ bucket, int E) {
    int e = blockIdx.x * blockDim.x + threadIdx.x;
    if (e < E) {
        int p = atomicAdd(&cur[dst[e]], 1);
        bucket[p] = (ushort)src[e];
    }
}

// ---------------- gather: z = xh + segment_sum(xh[src]) -> bf16 ----------------
__global__ void gather_kernel(const u16x8* __restrict__ xh8,
                              const int* __restrict__ start, const int* __restrict__ cnt,
                              const ushort* __restrict__ bucket,
                              u16x8* __restrict__ z8, int n) {
    int node = blockIdx.x * 16 + (threadIdx.x >> 4);
    int lane = threadIdx.x & 15;
    if (node >= n) return;
    int e0 = start[node];
    int eend = e0 + cnt[node];
    float a[8];
    #pragma unroll
    for (int j = 0; j < 8; ++j) a[j] = 0.f;
    int e = e0;
    for (; e + 8 <= eend; e += 8) {
        int s0 = bucket[e],     s1 = bucket[e + 1], s2 = bucket[e + 2], s3 = bucket[e + 3];
        int s4 = bucket[e + 4], s5 = bucket[e + 5], s6 = bucket[e + 6], s7 = bucket[e + 7];
        u16x8 v0 = xh8[(size_t)s0 * 16 + lane];
        u16x8 v1 = xh8[(size_t)s1 * 16 + lane];
        u16x8 v2 = xh8[(size_t)s2 * 16 + lane];
        u16x8 v3 = xh8[(size_t)s3 * 16 + lane];
        u16x8 v4 = xh8[(size_t)s4 * 16 + lane];
        u16x8 v5 = xh8[(size_t)s5 * 16 + lane];
        u16x8 v6 = xh8[(size_t)s6 * 16 + lane];
        u16x8 v7 = xh8[(size_t)s7 * 16 + lane];
        #pragma unroll
        for (int j = 0; j < 8; ++j) {
            a[j] += bf2f(v0[j]) + bf2f(v1[j]) + bf2f(v2[j]) + bf2f(v3[j])
                  + bf2f(v4[j]) + bf2f(v5[j]) + bf2f(v6[j]) + bf2f(v7[j]);
        }
    }
    for (; e + 4 <= eend; e += 4) {
        int s0 = bucket[e], s1 = bucket[e + 1], s2 = bucket[e + 2], s3 = bucket[e + 3];
        u16x8 v0 = xh8[(size_t)s0 * 16 + lane];
        u16x8 v1 = xh8[(size_t)s1 * 16 + lane];
        u16x8 v2 = xh8[(size_t)s2 * 16 + lane];
        u16x8 v3 = xh8[(size_t)s3 * 16 + lane];
        #pragma unroll
        for (int j = 0; j < 8; ++j)
            a[j] += bf2f(v0[j]) + bf2f(v1[j]) + bf2f(v2[j]) + bf2f(v3[j]);
    }
    for (; e < eend; ++e) {
        int s = bucket[e];
        u16x8 v = xh8[(size_t)s * 16 + lane];
        #pragma unroll
        for (int j = 0; j < 8; ++j) a[j] += bf2f(v[j]);
    }
    u16x8 xv = xh8[(size_t)node * 16 + lane];
    u16x8 zo;
    #pragma unroll
    for (int j = 0; j < 8; ++j) zo[j] = f2bf(a[j] + bf2f(xv[j]));
    z8[(size_t)node * 16 + lane] = zo;
}

// ---------------- fused MLP: h2 = relu(z@W1+b1)@W2 + b2 -> bf16, + BN stats ----------------
// (256,4): VGPR cap 128, est live ~120 -> 4 blocks/CU (was 3). If spill/regression,
// revert to (256,3).
__global__ __launch_bounds__(256, 4)
void fused_mlp(const ushort* __restrict__ Z, const ushort* __restrict__ wp,
               const float* __restrict__ b1, const float* __restrict__ b2,
               ushort* __restrict__ H2, float* __restrict__ stats, int nTiles) {
    __shared__ ushort h1s[4][2048];   // 4 tiles x (16 rows x 128 cols bf16)
    int wave = threadIdx.x >> 6, lane = threadIdx.x & 63;
    int rsel = lane & 15;
    int csel = lane >> 4;
    int nf0 = wave * 2;
    const ushort* w1p = wp;
    const ushort* w2p = wp + 16384;
    s16x8 w10[4], w11[4], w20[4], w21[4];
    #pragma unroll
    for (int ks = 0; ks < 4; ++ks) {
        w10[ks] = *(const s16x8*)(w1p + ((ks * 8 + nf0) * 64 + lane) * 8);
        w11[ks] = *(const s16x8*)(w1p + ((ks * 8 + nf0 + 1) * 64 + lane) * 8);
        w20[ks] = *(const s16x8*)(w2p + ((ks * 8 + nf0) * 64 + lane) * 8);
        w21[ks] = *(const s16x8*)(w2p + ((ks * 8 + nf0 + 1) * 64 + lane) * 8);
    }
    float b10 = b1[nf0 * 16 + rsel], b11 = b1[(nf0 + 1) * 16 + rsel];
    float b20 = b2[nf0 * 16 + rsel], b21 = b2[(nf0 + 1) * 16 + rsel];
    float s0 = 0.f, q0 = 0.f, s1 = 0.f, q1 = 0.f;
    int col0 = nf0 * 16 + rsel;

    for (int t0 = blockIdx.x * 4; t0 < nTiles; t0 += gridDim.x * 4) {
        __syncthreads();   // LDS free from previous iteration
        // ---- phase 1: h1 tiles -> LDS ----
        #pragma unroll
        for (int t = 0; t < 4; ++t) {
            int tile = t0 + t;
            if (tile < nTiles) {
                const ushort* aP = Z + ((size_t)tile * 16 + rsel) * D + csel * 8;
                s16x8 a0 = *(const s16x8*)(aP);
                s16x8 a1 = *(const s16x8*)(aP + 32);
                s16x8 a2 = *(const s16x8*)(aP + 64);
                s16x8 a3 = *(const s16x8*)(aP + 96);
                f32x4 acc0 = (f32x4){0.f, 0.f, 0.f, 0.f};
                f32x4 acc1 = (f32x4){0.f, 0.f, 0.f, 0.f};
                acc0 = __builtin_amdgcn_mfma_f32_16x16x32_bf16(a0, w10[0], acc0, 0, 0, 0);
                acc1 = __builtin_amdgcn_mfma_f32_16x16x32_bf16(a0, w11[0], acc1, 0, 0, 0);
                acc0 = __builtin_amdgcn_mfma_f32_16x16x32_bf16(a1, w10[1], acc0, 0, 0, 0);
                acc1 = __builtin_amdgcn_mfma_f32_16x16x32_bf16(a1, w11[1], acc1, 0, 0, 0);
                acc0 = __builtin_amdgcn_mfma_f32_16x16x32_bf16(a2, w10[2], acc0, 0, 0, 0);
                acc1 = __builtin_amdgcn_mfma_f32_16x16x32_bf16(a2, w11[2], acc1, 0, 0, 0);
                acc0 = __builtin_amdgcn_mfma_f32_16x16x32_bf16(a3, w10[3], acc0, 0, 0, 0);
                acc1 = __builtin_amdgcn_mfma_f32_16x16x32_bf16(a3, w11[3], acc1, 0, 0, 0);
                char* tb = (char*)h1s[t];
                int c20 = col0 * 2, c21 = (col0 + 16) * 2;
                #pragma unroll
                for (int r = 0; r < 4; ++r) {
                    int rr = csel * 4 + r;
                    int sw = (rr & 7) << 4;
                    *(ushort*)(tb + rr * 256 + (c20 ^ sw)) = f2bf(fmaxf(acc0[r] + b10, 0.f));
                    *(ushort*)(tb + rr * 256 + (c21 ^ sw)) = f2bf(fmaxf(acc1[r] + b11, 0.f));
                }
            }
        }
        __syncthreads();
        // ---- phase 2: gemm2 from LDS h1, h2 -> bf16 global + reg stats ----
        #pragma unroll
        for (int t = 0; t < 4; ++t) {
            int tile = t0 + t;
            if (tile < nTiles) {
                const char* tb = (const char*)h1s[t];
                int sw = (rsel & 7) << 4;
                s16x8 a0 = *(const s16x8*)(tb + rsel * 256 + ((csel * 16) ^ sw));
                s16x8 a1 = *(const s16x8*)(tb + rsel * 256 + ((64 + csel * 16) ^ sw));
                s16x8 a2 = *(const s16x8*)(tb + rsel * 256 + ((128 + csel * 16) ^ sw));
                s16x8 a3 = *(const s16x8*)(tb + rsel * 256 + ((192 + csel * 16) ^ sw));
                f32x4 acc0 = (f32x4){0.f, 0.f, 0.f, 0.f};
                f32x4 acc1 = (f32x4){0.f, 0.f, 0.f, 0.f};
                acc0 = __builtin_amdgcn_mfma_f32_16x16x32_bf16(a0, w20[0], acc0, 0, 0, 0);
                acc1 = __builtin_amdgcn_mfma_f32_16x16x32_bf16(a0, w21[0], acc1, 0, 0, 0);
                acc0 = __builtin_amdgcn_mfma_f32_16x16x32_bf16(a1, w20[1], acc0, 0, 0, 0);
                acc1 = __builtin_amdgcn_mfma_f32_16x16x32_bf16(a1, w21[1], acc1, 0, 0, 0);
                acc0 = __builtin_amdgcn_mfma_f32_16x16x32_bf16(a2, w20[2], acc0, 0, 0, 0);
                acc1 = __builtin_amdgcn_mfma_f32_16x16x32_bf16(a2, w21[2], acc1, 0, 0, 0);
                acc0 = __builtin_amdgcn_mfma_f32_16x16x32_bf16(a3, w20[3], acc0, 0, 0, 0);
                acc1 = __builtin_amdgcn_mfma_f32_16x16x32_bf16(a3, w21[3], acc1, 0, 0, 0);
                int orow = tile * 16 + csel * 4;
                #pragma unroll
                for (int r = 0; r < 4; ++r) {
                    float v0 = acc0[r] + b20;
                    float v1 = acc1[r] + b21;
                    H2[(size_t)(orow + r) * D + col0]      = f2bf(v0);
                    H2[(size_t)(orow + r) * D + col0 + 16] = f2bf(v1);
                    s0 += v0; q0 += v0 * v0;
                    s1 += v1; q1 += v1 * v1;
                }
            }
        }
    }
    // ---- flush stats ----
    s0 += __shfl_xor(s0, 16); s0 += __shfl_xor(s0, 32);
    q0 += __shfl_xor(q0, 16); q0 += __shfl_xor(q0, 32);
    s1 += __shfl_xor(s1, 16); s1 += __shfl_xor(s1, 32);
    q1 += __shfl_xor(q1, 16); q1 += __shfl_xor(q1, 32);
    if (csel == 0) {
        atomicAdd(&stats[col0], s0);
        atomicAdd(&stats[128 + col0], q0);
        atomicAdd(&stats[col0 + 16], s1);
        atomicAdd(&stats[128 + col0 + 16], q1);
    }
}

// ---------------- BN normalize + residual (bf16 h2 + bf16 x -> fp32 out) ----------------
__global__ void bn_final(const u16x8* __restrict__ h8, const u16x8* __restrict__ xh8,
                         float* __restrict__ out,
                         const float* __restrict__ stats, const float* __restrict__ gamma,
                         const float* __restrict__ beta, int n8, float invN) {
    int i = blockIdx.x * blockDim.x + threadIdx.x;
    if (i >= n8) return;
    int cg = (i & 15) * 8;   // channel base for this ushort8
    u16x8 hv = h8[i];
    u16x8 xv = xh8[i];
    float o[8];
    #pragma unroll
    for (int j = 0; j < 8; ++j) {
        int c = cg + j;
        float m = stats[c] * invN;
        float var = stats[128 + c] * invN - m * m;
        float iv = rsqrtf(var + 1e-5f);
        o[j] = (bf2f(hv[j]) - m) * iv * gamma[c] + beta[c] + bf2f(xv[j]);
    }
    float4* o4 = (float4*)(out + (size_t)i * 8);
    o4[0] = make_float4(o[0], o[1], o[2], o[3]);
    o4[1] = make_float4(o[4], o[5], o[6], o[7]);
}

extern "C" void kernel_launch(void* const* d_in, const int* in_sizes, int n_in,
                              void* d_out, int out_size, void* d_ws, size_t ws_size,
                              hipStream_t stream) {
    const float* x     = (const float*)d_in[0];
    const int*   ei    = (const int*)d_in[1];
    const float* W1    = (const float*)d_in[2];
    const float* b1    = (const float*)d_in[3];
    const float* W2    = (const float*)d_in[4];
    const float* b2    = (const float*)d_in[5];
    const float* gamma = (const float*)d_in[6];
    const float* beta  = (const float*)d_in[7];
    float* out = (float*)d_out;

    int N = in_sizes[0] / D;   // 50000
    int E = in_sizes[1] / 2;   // 600000
    const int* src = ei;
    const int* dst = ei + E;

    size_t NB = (size_t)N * D;
    ushort* xh   = (ushort*)d_ws;          // NB ushorts
    ushort* z    = xh + NB;                // NB ushorts
    ushort* h2   = z + NB;                 // NB ushorts
    ushort* wp   = h2 + NB;                // 2*16384
    float*  stats = (float*)(wp + 32768);  // 256 floats (16B aligned)
    int*    cnt  = (int*)(stats + 256);    // N
    int*    tot  = cnt + N;                // 1
    int*    startA = tot + 1;              // N
    int*    cur  = startA + N;             // N
    ushort* bucket = (ushort*)(cur + N);   // E ushorts

    const int B = 256;
    int nz = 256 + N + 1;   // stats + cnt + tot (contiguous ints)
    zero_kernel<<<(nz + B - 1) / B, B, 0, stream>>>((int*)stats, nz);

    int n4 = (int)(NB / 4);
    prep_kernel<<<2048, B, 0, stream>>>((const float4*)x, (ushort4*)xh, n4,
                                        dst, cnt, E, W1, W2, wp);
    alloc_kernel<<<(N + B - 1) / B, B, 0, stream>>>(cnt, startA, cur, tot, N);
    fill_kernel<<<(E + B - 1) / B, B, 0, stream>>>(src, dst, cur, bucket, E);
    gather_kernel<<<(N + 15) / 16, B, 0, stream>>>((const u16x8*)xh, startA, cnt, bucket,
                                                   (u16x8*)z, N);
    int nTiles = (N + 15) / 16;   // 3125
    fused_mlp<<<782, B, 0, stream>>>(z, wp, b1, b2, h2, stats, nTiles);
    int n8 = (int)(NB / 8);
    bn_final<<<(n8 + B - 1) / B, B, 0, stream>>>((const u16x8*)h2, (const u16x8*)xh,
                                                 out, stats, gamma, beta, n8,
                                                 1.0f / (float)N);
}